// Round 1
// baseline (848.545 us; speedup 1.0000x reference)
//
#include <hip/hip_runtime.h>
#include <math.h>

#define HW_PIX 65536
#define H_BEV 256
#define W_BEV 256
#define C_FEAT 128
#define F_FRAMES 4
#define N_AGENTS 5

// softmax(0.5^i, i=0..3) computed in double
__device__ __forceinline__ double hist_weight(int i) {
    const double e0 = exp(1.0);
    const double e1 = exp(0.5);
    const double e2 = exp(0.25);
    const double e3 = exp(0.125);
    const double s = e0 + e1 + e2 + e3;
    double v = (i == 0) ? e0 : (i == 1) ? e1 : (i == 2) ? e2 : e3;
    return v / s;
}

// Kernel 1: for each (frame, chunk) plane, compute hw[frame] * s(pixel) and
// store as a float plane in ws.  chunk0 = agents {0:ego, 1, 2}; chunk1 = agent {4}
// (chunk1 ego = agent 3 is mathematically unused: softmax over 1 elem == 1).
// Each thread handles 4 consecutive pixels via float4 loads.
__global__ __launch_bounds__(256) void score_kernel(
        const float* __restrict__ hist, const float* __restrict__ mlp_w,
        const float* __restrict__ mlp_b, float* __restrict__ ws) {
    const int fc = blockIdx.y;            // 0..7
    const int frame = fc >> 1;
    const int chunk = fc & 1;
    const int p = (blockIdx.x * blockDim.x + threadIdx.x) << 2;  // pixel base

    const float* base = hist + (size_t)frame * N_AGENTS * C_FEAT * HW_PIX;
    const double hwq = hist_weight(frame);
    const double bias = (double)mlp_b[0];
    float* outp = ws + (size_t)fc * HW_PIX + p;

    if (chunk == 0) {
        const float* a0 = base + (size_t)0 * C_FEAT * HW_PIX + p;
        const float* a1 = base + (size_t)1 * C_FEAT * HW_PIX + p;
        const float* a2 = base + (size_t)2 * C_FEAT * HW_PIX + p;
        double d1[4] = {0, 0, 0, 0}, d2[4] = {0, 0, 0, 0};
        double q1[4] = {0, 0, 0, 0}, q2[4] = {0, 0, 0, 0};
        #pragma unroll 8
        for (int c = 0; c < C_FEAT; ++c) {
            const float4 e  = *(const float4*)(a0 + (size_t)c * HW_PIX);
            const float4 n1 = *(const float4*)(a1 + (size_t)c * HW_PIX);
            const float4 n2 = *(const float4*)(a2 + (size_t)c * HW_PIX);
            const double wc = (double)mlp_w[c];   // uniform -> scalar load
            const float* ev  = &e.x;
            const float* n1v = &n1.x;
            const float* n2v = &n2.x;
            #pragma unroll
            for (int k = 0; k < 4; ++k) {
                d1[k] += (double)ev[k] * (double)n1v[k];
                d2[k] += (double)ev[k] * (double)n2v[k];
                q1[k] += wc * (double)n1v[k];
                q2[k] += wc * (double)n2v[k];
            }
        }
        const double scale = 0.08838834764831844506;  // 1/sqrt(128)
        #pragma unroll
        for (int k = 0; k < 4; ++k) {
            double x1 = d1[k] * scale, x2 = d2[k] * scale;
            double m = fmax(x1, x2);
            double e1 = exp(x1 - m), e2 = exp(x2 - m);
            double inv = 1.0 / (e1 + e2);
            double ctxw = (e1 * q1[k] + e2 * q2[k]) * inv + bias;
            double s = 1.0 / (1.0 + exp(-ctxw));
            outp[k] = (float)(hwq * s);
        }
    } else {
        const float* a4 = base + (size_t)4 * C_FEAT * HW_PIX + p;
        double q[4] = {0, 0, 0, 0};
        #pragma unroll 8
        for (int c = 0; c < C_FEAT; ++c) {
            const float4 n = *(const float4*)(a4 + (size_t)c * HW_PIX);
            const double wc = (double)mlp_w[c];
            const float* nv = &n.x;
            #pragma unroll
            for (int k = 0; k < 4; ++k) q[k] += wc * (double)nv[k];
        }
        #pragma unroll
        for (int k = 0; k < 4; ++k) {
            double s = 1.0 / (1.0 + exp(-(q[k] + bias)));
            outp[k] = (float)(hwq * s);
        }
    }
}

// Kernel 2: acc(pixel, chunk) = sum over 4 frame planes (f64), threshold > 0.5.
__global__ __launch_bounds__(256) void mask_kernel(
        const float* __restrict__ planes, float* __restrict__ mask) {
    const int p = blockIdx.x * blockDim.x + threadIdx.x;
    if (p >= HW_PIX) return;
    #pragma unroll
    for (int j = 0; j < 2; ++j) {
        double acc = 0.0;
        #pragma unroll
        for (int i = 0; i < F_FRAMES; ++i)
            acc += (double)planes[(size_t)(i * 2 + j) * HW_PIX + p];
        mask[(size_t)j * HW_PIX + p] = (acc > 0.5) ? 1.0f : 0.0f;
    }
}

// Kernel 3: 3x3 max-pool (pad -inf == clamped window on {0,1} data) + write
// all 5 output planes. Agents 0,3 (egos) are identically 1.0.
__global__ __launch_bounds__(256) void pool_kernel(
        const float* __restrict__ mask, float* __restrict__ out) {
    const int p = blockIdx.x * blockDim.x + threadIdx.x;
    if (p >= HW_PIX) return;
    const int y = p >> 8, x = p & 255;
    float m[2];
    #pragma unroll
    for (int j = 0; j < 2; ++j) {
        float mx = 0.0f;
        for (int dy = -1; dy <= 1; ++dy) {
            int yy = y + dy;
            if (yy < 0 || yy >= H_BEV) continue;
            for (int dx = -1; dx <= 1; ++dx) {
                int xx = x + dx;
                if (xx < 0 || xx >= W_BEV) continue;
                mx = fmaxf(mx, mask[(size_t)j * HW_PIX + (yy << 8) + xx]);
            }
        }
        m[j] = mx;
    }
    out[(size_t)0 * HW_PIX + p] = 1.0f;   // agent 0: chunk0 ego
    out[(size_t)1 * HW_PIX + p] = m[0];   // agent 1: chunk0 neighbor
    out[(size_t)2 * HW_PIX + p] = m[0];   // agent 2: chunk0 neighbor (same s)
    out[(size_t)3 * HW_PIX + p] = 1.0f;   // agent 3: chunk1 ego
    out[(size_t)4 * HW_PIX + p] = m[1];   // agent 4: chunk1 neighbor
}

extern "C" void kernel_launch(void* const* d_in, const int* in_sizes, int n_in,
                              void* d_out, int out_size, void* d_ws, size_t ws_size,
                              hipStream_t stream) {
    const float* hist  = (const float*)d_in[0];
    const float* mlp_w = (const float*)d_in[1];
    const float* mlp_b = (const float*)d_in[2];
    float* ws   = (float*)d_ws;              // 8 score planes + 2 mask planes
    float* mask = ws + (size_t)8 * HW_PIX;
    float* out  = (float*)d_out;

    dim3 g1(HW_PIX / (4 * 256), 8);          // 64 x 8 blocks
    score_kernel<<<g1, 256, 0, stream>>>(hist, mlp_w, mlp_b, ws);
    mask_kernel<<<HW_PIX / 256, 256, 0, stream>>>(ws, mask);
    pool_kernel<<<HW_PIX / 256, 256, 0, stream>>>(mask, out);
}

// Round 2
// 840.965 us; speedup vs baseline: 1.0090x; 1.0090x over previous
//
#include <hip/hip_runtime.h>
#include <math.h>

#define HW_PIX 65536
#define H_BEV 256
#define W_BEV 256
#define C_FEAT 128
#define F_FRAMES 4
#define N_AGENTS 5
#define CSPLIT 4
#define CCHUNK (C_FEAT / CSPLIT)   // 32 channels per block

struct d4 { double x, y, z, w; };

__device__ __forceinline__ void fma4(d4& a, const float4 u, const float4 v) {
    a.x += (double)u.x * (double)v.x;
    a.y += (double)u.y * (double)v.y;
    a.z += (double)u.z * (double)v.z;
    a.w += (double)u.w * (double)v.w;
}
__device__ __forceinline__ void fma4s(d4& a, const double w, const float4 v) {
    a.x += w * (double)v.x;
    a.y += w * (double)v.y;
    a.z += w * (double)v.z;
    a.w += w * (double)v.w;
}

// softmax(0.5^i, i=0..3) in double
__device__ __forceinline__ double hist_weight(int i) {
    const double e0 = exp(1.0), e1 = exp(0.5), e2 = exp(0.25), e3 = exp(0.125);
    const double s = e0 + e1 + e2 + e3;
    double v = (i == 0) ? e0 : (i == 1) ? e1 : (i == 2) ? e2 : e3;
    return v / s;
}

// Kernel 1: uniform-work dot kernel. Block = (frame, channel-quarter);
// each thread owns 4 consecutive pixels and accumulates the 5 dot partials
// d1=e.n1, d2=e.n2, q1=w.n1, q2=w.n2, q4=w.n4 over 32 channels in f64.
// Partials layout: part[fs=frame*4+split][dot(5)][HW_PIX] as double.
__global__ __launch_bounds__(256) void dot_kernel(
        const float* __restrict__ hist, const float* __restrict__ mlp_w,
        double* __restrict__ part) {
    const int fs = blockIdx.y;            // 0..15
    const int frame = fs >> 2;
    const int split = fs & 3;
    const int p = (blockIdx.x * blockDim.x + threadIdx.x) << 2;
    const int c0 = split * CCHUNK;

    const float* base = hist + (size_t)frame * N_AGENTS * C_FEAT * HW_PIX
                             + (size_t)c0 * HW_PIX + p;
    const float* a0 = base;                                   // ego (agent 0)
    const float* a1 = base + (size_t)1 * C_FEAT * HW_PIX;     // agent 1
    const float* a2 = base + (size_t)2 * C_FEAT * HW_PIX;     // agent 2
    const float* a4 = base + (size_t)4 * C_FEAT * HW_PIX;     // agent 4

    d4 d1 = {0, 0, 0, 0}, d2 = {0, 0, 0, 0};
    d4 q1 = {0, 0, 0, 0}, q2 = {0, 0, 0, 0}, q4 = {0, 0, 0, 0};

    #pragma unroll 4
    for (int c = 0; c < CCHUNK; ++c) {
        const float4 e  = *(const float4*)(a0 + (size_t)c * HW_PIX);
        const float4 n1 = *(const float4*)(a1 + (size_t)c * HW_PIX);
        const float4 n2 = *(const float4*)(a2 + (size_t)c * HW_PIX);
        const float4 n4 = *(const float4*)(a4 + (size_t)c * HW_PIX);
        const double wc = (double)mlp_w[c0 + c];   // uniform -> scalar
        fma4(d1, e, n1);
        fma4(d2, e, n2);
        fma4s(q1, wc, n1);
        fma4s(q2, wc, n2);
        fma4s(q4, wc, n4);
    }

    double* pb = part + ((size_t)fs * 5) * HW_PIX + p;
    *(double2*)(pb + 0 * HW_PIX)     = make_double2(d1.x, d1.y);
    *(double2*)(pb + 0 * HW_PIX + 2) = make_double2(d1.z, d1.w);
    *(double2*)(pb + 1 * HW_PIX)     = make_double2(d2.x, d2.y);
    *(double2*)(pb + 1 * HW_PIX + 2) = make_double2(d2.z, d2.w);
    *(double2*)(pb + 2 * HW_PIX)     = make_double2(q1.x, q1.y);
    *(double2*)(pb + 2 * HW_PIX + 2) = make_double2(q1.z, q1.w);
    *(double2*)(pb + 3 * HW_PIX)     = make_double2(q2.x, q2.y);
    *(double2*)(pb + 3 * HW_PIX + 2) = make_double2(q2.z, q2.w);
    *(double2*)(pb + 4 * HW_PIX)     = make_double2(q4.x, q4.y);
    *(double2*)(pb + 4 * HW_PIX + 2) = make_double2(q4.z, q4.w);
}

// Kernel 2: per pixel, reduce the 4 channel-splits per frame, softmax over
// {d1,d2} -> ctx.w, sigmoid, history-weight sum over frames, threshold.
__global__ __launch_bounds__(256) void mask_kernel(
        const double* __restrict__ part, const float* __restrict__ mlp_b,
        float* __restrict__ mask) {
    const int p = blockIdx.x * blockDim.x + threadIdx.x;
    if (p >= HW_PIX) return;
    const double bias = (double)mlp_b[0];
    const double scale = 0.08838834764831844506;  // 1/sqrt(128)
    double acc0 = 0.0, acc1 = 0.0;
    #pragma unroll
    for (int f = 0; f < F_FRAMES; ++f) {
        double d1 = 0, d2 = 0, q1 = 0, q2 = 0, q4 = 0;
        #pragma unroll
        for (int s = 0; s < CSPLIT; ++s) {
            const double* pp = part + ((size_t)(f * CSPLIT + s) * 5) * HW_PIX + p;
            d1 += pp[0 * HW_PIX];
            d2 += pp[1 * HW_PIX];
            q1 += pp[2 * HW_PIX];
            q2 += pp[3 * HW_PIX];
            q4 += pp[4 * HW_PIX];
        }
        double x1 = d1 * scale, x2 = d2 * scale;
        double m = fmax(x1, x2);
        double e1 = exp(x1 - m), e2 = exp(x2 - m);
        double ctxw = (e1 * q1 + e2 * q2) / (e1 + e2) + bias;
        double s0 = 1.0 / (1.0 + exp(-ctxw));        // chunk0 neighbor score
        double s1 = 1.0 / (1.0 + exp(-(q4 + bias))); // chunk1 neighbor score
        double hwf = hist_weight(f);
        acc0 += hwf * s0;
        acc1 += hwf * s1;
    }
    mask[p]          = (acc0 > 0.5) ? 1.0f : 0.0f;
    mask[HW_PIX + p] = (acc1 > 0.5) ? 1.0f : 0.0f;
}

// Kernel 3: 3x3 clamped max-pool on {0,1} masks; egos (agents 0,3) are 1.0.
__global__ __launch_bounds__(256) void pool_kernel(
        const float* __restrict__ mask, float* __restrict__ out) {
    const int p = blockIdx.x * blockDim.x + threadIdx.x;
    if (p >= HW_PIX) return;
    const int y = p >> 8, x = p & 255;
    float m[2];
    #pragma unroll
    for (int j = 0; j < 2; ++j) {
        float mx = 0.0f;
        for (int dy = -1; dy <= 1; ++dy) {
            int yy = y + dy;
            if (yy < 0 || yy >= H_BEV) continue;
            for (int dx = -1; dx <= 1; ++dx) {
                int xx = x + dx;
                if (xx < 0 || xx >= W_BEV) continue;
                mx = fmaxf(mx, mask[(size_t)j * HW_PIX + (yy << 8) + xx]);
            }
        }
        m[j] = mx;
    }
    out[(size_t)0 * HW_PIX + p] = 1.0f;
    out[(size_t)1 * HW_PIX + p] = m[0];
    out[(size_t)2 * HW_PIX + p] = m[0];
    out[(size_t)3 * HW_PIX + p] = 1.0f;
    out[(size_t)4 * HW_PIX + p] = m[1];
}

extern "C" void kernel_launch(void* const* d_in, const int* in_sizes, int n_in,
                              void* d_out, int out_size, void* d_ws, size_t ws_size,
                              hipStream_t stream) {
    const float* hist  = (const float*)d_in[0];
    const float* mlp_w = (const float*)d_in[1];
    const float* mlp_b = (const float*)d_in[2];
    double* part = (double*)d_ws;                     // 16*5*65536 doubles = 41.9 MB
    float*  mask = (float*)(part + (size_t)16 * 5 * HW_PIX);
    float*  out  = (float*)d_out;

    dim3 g1(HW_PIX / (4 * 256), F_FRAMES * CSPLIT);   // 64 x 16 = 1024 blocks
    dot_kernel<<<g1, 256, 0, stream>>>(hist, mlp_w, part);
    mask_kernel<<<HW_PIX / 256, 256, 0, stream>>>(part, mlp_b, mask);
    pool_kernel<<<HW_PIX / 256, 256, 0, stream>>>(mask, out);
}